// Round 1
// baseline (1132.177 us; speedup 1.0000x reference)
//
#include <hip/hip_runtime.h>

// Pseudo-3D DCN: B=2, C=32, T=8, H=W=192, K=9 (3x3, pad 1), groups=deform_groups=T.
// feat:   [B, 32, T, H, W]  f32
// offset: [B, 18, T, H, W]  f32  (per tap k: channel 2k = dy, 2k+1 = dx)
// weight: [T, 32, 32, 3, 3] f32
// out:    [B, 32, T, H, W]  f32
//
// One thread per output pixel, all 32 Cout accumulated in registers.
// Weights for slice t staged in LDS as [k][c][o] (36 KB), read as uniform
// float4 broadcasts in the inner loop.

#define CIN   32
#define COUT  32
#define TT    8
#define HH    192
#define WW    192
#define KK    9
#define HWSZ  (HH * WW)        // 36864
#define PLANE (TT * HWSZ)      // 294912 (channel stride in elements)

__global__ __launch_bounds__(256) void dcn_fp32_kernel(
    const float* __restrict__ feat,
    const float* __restrict__ offset,
    const float* __restrict__ weight,
    float* __restrict__ out)
{
    __shared__ float sw[KK * CIN * COUT];   // [k][c][o] -> 9*32*32*4 = 36 KB

    const int tid = threadIdx.x;
    const int t   = blockIdx.y;
    const int b   = blockIdx.z;

    // ---- stage weight[t] into LDS, transposed ----
    // global: wg[i], i = (o*CIN + c)*KK + k   (coalesced reads)
    // lds:    sw[(k*CIN + c)*COUT + o]        (scattered writes, one-time)
    {
        const float* wg = weight + (size_t)t * (COUT * CIN * KK);
        #pragma unroll
        for (int j = 0; j < (KK * CIN * COUT) / 256; ++j) {
            int i  = tid + j * 256;
            int k  = i % KK;
            int oc = i / KK;
            int c  = oc % CIN;
            int o  = oc / CIN;
            sw[(k * CIN + c) * COUT + o] = wg[i];
        }
    }
    __syncthreads();

    const int pix = blockIdx.x * 256 + tid;   // grid.x = HWSZ/256 = 144, exact
    const int h   = pix / WW;
    const int w   = pix % WW;

    float acc[COUT];
    #pragma unroll
    for (int o = 0; o < COUT; ++o) acc[o] = 0.0f;

    // ---- load the 18 offsets for this pixel ----
    const float* offp = offset + ((size_t)(b * 2 * KK) * TT + t) * HWSZ + pix;
    float offv[2 * KK];
    #pragma unroll
    for (int j = 0; j < 2 * KK; ++j) offv[j] = offp[(size_t)j * PLANE];

    const float* fbase = feat + ((size_t)(b * CIN) * TT + t) * HWSZ;

    for (int k = 0; k < KK; ++k) {
        const float dy = offv[2 * k];
        const float dx = offv[2 * k + 1];
        const float ys = (float)(h + k / 3 - 1) + dy;
        const float xs = (float)(w + k % 3 - 1) + dx;

        const float y0f = floorf(ys);
        const float x0f = floorf(xs);
        const float wy1 = ys - y0f;
        const float wx1 = xs - x0f;
        const float wy0 = 1.0f - wy1;
        const float wx0 = 1.0f - wx1;

        const int y0 = (int)y0f;
        const int x0 = (int)x0f;
        const int y1 = y0 + 1;
        const int x1 = x0 + 1;

        const bool vy0 = (y0 >= 0) && (y0 < HH);
        const bool vy1 = (y1 >= 0) && (y1 < HH);
        const bool vx0 = (x0 >= 0) && (x0 < WW);
        const bool vx1 = (x1 >= 0) && (x1 < WW);

        const int cy0 = min(max(y0, 0), HH - 1);
        const int cy1 = min(max(y1, 0), HH - 1);
        const int cx0 = min(max(x0, 0), WW - 1);
        const int cx1 = min(max(x1, 0), WW - 1);

        // masked bilinear weights (zero-padding semantics, matches reference)
        const float w00 = wy0 * wx0 * ((vy0 && vx0) ? 1.0f : 0.0f);
        const float w01 = wy0 * wx1 * ((vy0 && vx1) ? 1.0f : 0.0f);
        const float w10 = wy1 * wx0 * ((vy1 && vx0) ? 1.0f : 0.0f);
        const float w11 = wy1 * wx1 * ((vy1 && vx1) ? 1.0f : 0.0f);

        const int i00 = cy0 * WW + cx0;
        const int i01 = cy0 * WW + cx1;
        const int i10 = cy1 * WW + cx0;
        const int i11 = cy1 * WW + cx1;

        const float*  sp   = fbase;
        const float4* wrow = (const float4*)&sw[k * CIN * COUT];

        for (int c = 0; c < CIN; ++c) {
            const float v = w00 * sp[i00] + w01 * sp[i01]
                          + w10 * sp[i10] + w11 * sp[i11];
            const float4* wp = wrow + c * (COUT / 4);
            #pragma unroll
            for (int o4 = 0; o4 < COUT / 4; ++o4) {
                const float4 wv = wp[o4];
                acc[4 * o4 + 0] += v * wv.x;
                acc[4 * o4 + 1] += v * wv.y;
                acc[4 * o4 + 2] += v * wv.z;
                acc[4 * o4 + 3] += v * wv.w;
            }
            sp += PLANE;
        }
    }

    // ---- write out [B, COUT, T, H, W] ----
    float* op = out + ((size_t)(b * COUT) * TT + t) * HWSZ + pix;
    #pragma unroll
    for (int o = 0; o < COUT; ++o) op[(size_t)o * PLANE] = acc[o];
}

extern "C" void kernel_launch(void* const* d_in, const int* in_sizes, int n_in,
                              void* d_out, int out_size, void* d_ws, size_t ws_size,
                              hipStream_t stream) {
    const float* feat   = (const float*)d_in[0];
    const float* offset = (const float*)d_in[1];
    const float* weight = (const float*)d_in[2];
    float* out = (float*)d_out;

    dim3 grid(HWSZ / 256, TT, 2 /*B*/);
    dim3 block(256, 1, 1);
    dcn_fp32_kernel<<<grid, block, 0, stream>>>(feat, offset, weight, out);
}

// Round 2
// 800.472 us; speedup vs baseline: 1.4144x; 1.4144x over previous
//
#include <hip/hip_runtime.h>

// Pseudo-3D DCN: B=2, C=32, T=8, H=W=192, K=9 (3x3, pad 1), groups=deform_groups=T.
// feat:   [B, 32, T, H, W]  f32
// offset: [B, 18, T, H, W]  f32  (per tap k: 2k = dy, 2k+1 = dx)
// weight: [T, 32, 32, 3, 3] f32
// out:    [B, 32, T, H, W]  f32
//
// Round 2: pre-transpose feat to channels-last [B,T,H,W,C] in d_ws so each
// bilinear corner is 8 contiguous float4 loads (full cacheline use) instead
// of 32 scalar gathers at 1.18 MB stride. Round-1 kernel kept as fallback if
// ws_size is too small.

#define CIN   32
#define COUT  32
#define TT    8
#define HH    192
#define WW    192
#define KK    9
#define HWSZ  (HH * WW)        // 36864
#define PLANE (TT * HWSZ)      // 294912 (channel stride in elements)

// ---------------------------------------------------------------------------
// Transpose: feat [B,C,T,H,W] -> tf [B,T,H,W,C]   (f32)
// grid (HWSZ/64, T, B); block 256. Each block: 32 channels x 64 pixels.
// ---------------------------------------------------------------------------
__global__ __launch_bounds__(256) void transpose_cl_kernel(
    const float* __restrict__ feat, float* __restrict__ tf)
{
    __shared__ float tile[CIN][65];   // +1 pad: conflict-free both phases

    const int p0 = blockIdx.x * 64;
    const int t  = blockIdx.y;
    const int b  = blockIdx.z;

    const float* src = feat + (size_t)b * CIN * PLANE + (size_t)t * HWSZ + p0;
    #pragma unroll
    for (int it = 0; it < 8; ++it) {
        int i = it * 256 + threadIdx.x;
        int c = i >> 6, p = i & 63;                    // p fastest -> coalesced
        tile[c][p] = src[(size_t)c * PLANE + p];
    }
    __syncthreads();

    float* dst = tf + ((size_t)(b * TT + t) * HWSZ + p0) * CIN;
    #pragma unroll
    for (int it = 0; it < 8; ++it) {
        int i = it * 256 + threadIdx.x;
        int p = i >> 5, c = i & 31;                    // c fastest -> coalesced
        dst[(size_t)p * CIN + c] = tile[c][p];
    }
}

// ---------------------------------------------------------------------------
// Main kernel, channels-last feat. One thread per output pixel, 32 Cout in
// registers. Weights for slice t staged in LDS as [k][c][o] (36 KB), read as
// uniform float4 broadcasts. Block = 64x4 pixel tile.
// ---------------------------------------------------------------------------
__global__ __launch_bounds__(256) void dcn_cl_kernel(
    const float* __restrict__ tf,
    const float* __restrict__ offset,
    const float* __restrict__ weight,
    float* __restrict__ out)
{
    __shared__ float sw[KK * CIN * COUT];   // [k][c][o] -> 36 KB

    const int tid = threadIdx.y * 64 + threadIdx.x;
    const int bt  = blockIdx.z;            // b*TT + t
    const int t   = bt & (TT - 1);
    const int b   = bt >> 3;

    {   // stage weight[t] -> LDS transposed [k][c][o]
        const float* wg = weight + (size_t)t * (COUT * CIN * KK);
        #pragma unroll
        for (int j = 0; j < (KK * CIN * COUT) / 256; ++j) {
            int i  = tid + j * 256;
            int k  = i % KK;
            int oc = i / KK;
            sw[(k * CIN + (oc % CIN)) * COUT + (oc / CIN)] = wg[i];
        }
    }
    __syncthreads();

    const int w   = blockIdx.x * 64 + threadIdx.x;
    const int h   = blockIdx.y * 4 + threadIdx.y;
    const int pix = h * WW + w;

    float acc[COUT];
    #pragma unroll
    for (int o = 0; o < COUT; ++o) acc[o] = 0.0f;

    // 18 offsets for this pixel (coalesced, plane-strided)
    const float* offp = offset + (size_t)b * 2 * KK * PLANE + (size_t)t * HWSZ + pix;
    float offv[2 * KK];
    #pragma unroll
    for (int j = 0; j < 2 * KK; ++j) offv[j] = offp[(size_t)j * PLANE];

    const float4* fb = (const float4*)(tf + (size_t)bt * HWSZ * CIN);  // [pix][c], 8 float4/pix

    for (int k = 0; k < KK; ++k) {
        const float ys = (float)(h + k / 3 - 1) + offv[2 * k];
        const float xs = (float)(w + k % 3 - 1) + offv[2 * k + 1];

        const float y0f = floorf(ys);
        const float x0f = floorf(xs);
        const float wy1 = ys - y0f;
        const float wx1 = xs - x0f;
        const float wy0 = 1.0f - wy1;
        const float wx0 = 1.0f - wx1;

        const int y0 = (int)y0f, x0 = (int)x0f;
        const int y1 = y0 + 1,  x1 = x0 + 1;

        const bool vy0 = (y0 >= 0) && (y0 < HH);
        const bool vy1 = (y1 >= 0) && (y1 < HH);
        const bool vx0 = (x0 >= 0) && (x0 < WW);
        const bool vx1 = (x1 >= 0) && (x1 < WW);

        const int cy0 = min(max(y0, 0), HH - 1);
        const int cy1 = min(max(y1, 0), HH - 1);
        const int cx0 = min(max(x0, 0), WW - 1);
        const int cx1 = min(max(x1, 0), WW - 1);

        const float w00 = wy0 * wx0 * ((vy0 && vx0) ? 1.0f : 0.0f);
        const float w01 = wy0 * wx1 * ((vy0 && vx1) ? 1.0f : 0.0f);
        const float w10 = wy1 * wx0 * ((vy1 && vx0) ? 1.0f : 0.0f);
        const float w11 = wy1 * wx1 * ((vy1 && vx1) ? 1.0f : 0.0f);

        const float4* p00 = fb + (size_t)(cy0 * WW + cx0) * (CIN / 4);
        const float4* p01 = fb + (size_t)(cy0 * WW + cx1) * (CIN / 4);
        const float4* p10 = fb + (size_t)(cy1 * WW + cx0) * (CIN / 4);
        const float4* p11 = fb + (size_t)(cy1 * WW + cx1) * (CIN / 4);

        const float4* wrow = (const float4*)&sw[k * CIN * COUT];

        #pragma unroll
        for (int c4 = 0; c4 < CIN / 4; ++c4) {
            const float4 a0 = p00[c4];
            const float4 a1 = p01[c4];
            const float4 a2 = p10[c4];
            const float4 a3 = p11[c4];

            float v[4];
            v[0] = w00 * a0.x + w01 * a1.x + w10 * a2.x + w11 * a3.x;
            v[1] = w00 * a0.y + w01 * a1.y + w10 * a2.y + w11 * a3.y;
            v[2] = w00 * a0.z + w01 * a1.z + w10 * a2.z + w11 * a3.z;
            v[3] = w00 * a0.w + w01 * a1.w + w10 * a2.w + w11 * a3.w;

            #pragma unroll
            for (int j = 0; j < 4; ++j) {
                const float4* wp = wrow + (c4 * 4 + j) * (COUT / 4);
                #pragma unroll
                for (int o4 = 0; o4 < COUT / 4; ++o4) {
                    const float4 wv = wp[o4];
                    acc[4 * o4 + 0] += v[j] * wv.x;
                    acc[4 * o4 + 1] += v[j] * wv.y;
                    acc[4 * o4 + 2] += v[j] * wv.z;
                    acc[4 * o4 + 3] += v[j] * wv.w;
                }
            }
        }
    }

    float* op = out + (size_t)b * COUT * PLANE + (size_t)t * HWSZ + pix;
    #pragma unroll
    for (int o = 0; o < COUT; ++o) op[(size_t)o * PLANE] = acc[o];
}

// ---------------------------------------------------------------------------
// Round-1 fallback (channel-major gathers) — used only if ws_size too small.
// ---------------------------------------------------------------------------
__global__ __launch_bounds__(256) void dcn_fp32_kernel(
    const float* __restrict__ feat,
    const float* __restrict__ offset,
    const float* __restrict__ weight,
    float* __restrict__ out)
{
    __shared__ float sw[KK * CIN * COUT];
    const int tid = threadIdx.x;
    const int t   = blockIdx.y;
    const int b   = blockIdx.z;
    {
        const float* wg = weight + (size_t)t * (COUT * CIN * KK);
        #pragma unroll
        for (int j = 0; j < (KK * CIN * COUT) / 256; ++j) {
            int i  = tid + j * 256;
            int k  = i % KK;
            int oc = i / KK;
            sw[(k * CIN + (oc % CIN)) * COUT + (oc / CIN)] = wg[i];
        }
    }
    __syncthreads();

    const int pix = blockIdx.x * 256 + tid;
    const int h   = pix / WW;
    const int w   = pix % WW;

    float acc[COUT];
    #pragma unroll
    for (int o = 0; o < COUT; ++o) acc[o] = 0.0f;

    const float* offp = offset + ((size_t)(b * 2 * KK) * TT + t) * HWSZ + pix;
    float offv[2 * KK];
    #pragma unroll
    for (int j = 0; j < 2 * KK; ++j) offv[j] = offp[(size_t)j * PLANE];

    const float* fbase = feat + ((size_t)(b * CIN) * TT + t) * HWSZ;

    for (int k = 0; k < KK; ++k) {
        const float ys = (float)(h + k / 3 - 1) + offv[2 * k];
        const float xs = (float)(w + k % 3 - 1) + offv[2 * k + 1];
        const float y0f = floorf(ys), x0f = floorf(xs);
        const float wy1 = ys - y0f, wx1 = xs - x0f;
        const float wy0 = 1.0f - wy1, wx0 = 1.0f - wx1;
        const int y0 = (int)y0f, x0 = (int)x0f, y1 = y0 + 1, x1 = x0 + 1;
        const bool vy0 = (y0 >= 0) && (y0 < HH), vy1 = (y1 >= 0) && (y1 < HH);
        const bool vx0 = (x0 >= 0) && (x0 < WW), vx1 = (x1 >= 0) && (x1 < WW);
        const int cy0 = min(max(y0, 0), HH - 1), cy1 = min(max(y1, 0), HH - 1);
        const int cx0 = min(max(x0, 0), WW - 1), cx1 = min(max(x1, 0), WW - 1);
        const float w00 = wy0 * wx0 * ((vy0 && vx0) ? 1.0f : 0.0f);
        const float w01 = wy0 * wx1 * ((vy0 && vx1) ? 1.0f : 0.0f);
        const float w10 = wy1 * wx0 * ((vy1 && vx0) ? 1.0f : 0.0f);
        const float w11 = wy1 * wx1 * ((vy1 && vx1) ? 1.0f : 0.0f);
        const int i00 = cy0 * WW + cx0, i01 = cy0 * WW + cx1;
        const int i10 = cy1 * WW + cx0, i11 = cy1 * WW + cx1;

        const float*  sp   = fbase;
        const float4* wrow = (const float4*)&sw[k * CIN * COUT];
        for (int c = 0; c < CIN; ++c) {
            const float v = w00 * sp[i00] + w01 * sp[i01]
                          + w10 * sp[i10] + w11 * sp[i11];
            const float4* wp = wrow + c * (COUT / 4);
            #pragma unroll
            for (int o4 = 0; o4 < COUT / 4; ++o4) {
                const float4 wv = wp[o4];
                acc[4 * o4 + 0] += v * wv.x;
                acc[4 * o4 + 1] += v * wv.y;
                acc[4 * o4 + 2] += v * wv.z;
                acc[4 * o4 + 3] += v * wv.w;
            }
            sp += PLANE;
        }
    }

    float* op = out + ((size_t)(b * COUT) * TT + t) * HWSZ + pix;
    #pragma unroll
    for (int o = 0; o < COUT; ++o) op[(size_t)o * PLANE] = acc[o];
}

extern "C" void kernel_launch(void* const* d_in, const int* in_sizes, int n_in,
                              void* d_out, int out_size, void* d_ws, size_t ws_size,
                              hipStream_t stream) {
    const float* feat   = (const float*)d_in[0];
    const float* offset = (const float*)d_in[1];
    const float* weight = (const float*)d_in[2];
    float* out = (float*)d_out;

    const size_t need = (size_t)2 * TT * HWSZ * CIN * sizeof(float);  // 75.5 MB
    if (ws_size >= need) {
        float* tf = (float*)d_ws;
        dim3 tgrid(HWSZ / 64, TT, 2);
        transpose_cl_kernel<<<tgrid, dim3(256, 1, 1), 0, stream>>>(feat, tf);
        dim3 grid(WW / 64, HH / 4, 2 * TT);
        dim3 block(64, 4, 1);
        dcn_cl_kernel<<<grid, block, 0, stream>>>(tf, offset, weight, out);
    } else {
        dim3 grid(HWSZ / 256, TT, 2);
        dcn_fp32_kernel<<<grid, dim3(256, 1, 1), 0, stream>>>(feat, offset, weight, out);
    }
}

// Round 3
// 257.388 us; speedup vs baseline: 4.3987x; 3.1100x over previous
//
#include <hip/hip_runtime.h>
#include <hip/hip_bf16.h>

// Pseudo-3D DCN: B=2, C=32, T=8, H=W=192, K=9 (3x3, pad 1), groups=deform_groups=T.
// Round 3: bf16 channels-last feat + LDS halo staging + MFMA implicit GEMM.
//   - transpose_bf16_kernel: feat f32 [B,C,T,H,W] -> tf bf16 [B,T,H,W,C] (d_ws)
//   - wprep_kernel: weight f32 -> bf16 B-fragments [t][k][n][lane][j] (d_ws)
//   - dcn_mfma_kernel: 32x8 pixel tile/block, halo +-4 staged in LDS (80 B
//     stride for bank spread), per-tap bilinear straight into A-fragments,
//     mfma_f32_16x16x32_bf16 accumulation, weights held as reg B-frags.

#define CIN   32
#define COUT  32
#define TT    8
#define HH    192
#define WW    192
#define KK    9
#define HWSZ  (HH * WW)        // 36864
#define PLANE (TT * HWSZ)      // 294912

#define TILE_W 32
#define TILE_H 8
#define HALO   4
#define HROWS  (TILE_H + 2 * HALO + 1)   // 17
#define HCOLS  (TILE_W + 2 * HALO + 1)   // 41
// pixel-vector = 32ch bf16 = 64 B data, padded to 80 B (5 uint4) for banks

typedef __attribute__((ext_vector_type(8))) short short8;
typedef __attribute__((ext_vector_type(4))) float f32x4;

union U4S8 { uint4 u; short8 s; };

__device__ __forceinline__ float bl_lo(uint u) { return __uint_as_float(u << 16); }
__device__ __forceinline__ float bl_hi(uint u) { return __uint_as_float(u & 0xffff0000u); }

__device__ __forceinline__ uint pk_bf16(float lo, float hi) {
    float2 p; p.x = lo; p.y = hi;
    __hip_bfloat162 b = __float22bfloat162_rn(p);
    union { __hip_bfloat162 b; uint u; } cv; cv.b = b;
    return cv.u;
}

// bilinear-combine one dword (2 channels) from 4 corners, pack to bf16x2
__device__ __forceinline__ uint blerp_pack(uint a, uint b, uint c, uint d,
                                           float w00, float w01, float w10, float w11) {
    float lo = w00 * bl_lo(a) + w01 * bl_lo(b) + w10 * bl_lo(c) + w11 * bl_lo(d);
    float hi = w00 * bl_hi(a) + w01 * bl_hi(b) + w10 * bl_hi(c) + w11 * bl_hi(d);
    return pk_bf16(lo, hi);
}

// ---------------------------------------------------------------------------
// feat f32 [B,C,T,H,W] -> tf bf16 [B,T,H,W,C] (stored as uint = 2 channels)
// ---------------------------------------------------------------------------
__global__ __launch_bounds__(256) void transpose_bf16_kernel(
    const float* __restrict__ feat, uint* __restrict__ tf)
{
    __shared__ float tile[CIN][65];
    const int p0 = blockIdx.x * 64;
    const int t  = blockIdx.y;
    const int b  = blockIdx.z;

    const float* src = feat + (size_t)b * CIN * PLANE + (size_t)t * HWSZ + p0;
    #pragma unroll
    for (int it = 0; it < 8; ++it) {
        int i = it * 256 + threadIdx.x;
        int c = i >> 6, p = i & 63;
        tile[c][p] = src[(size_t)c * PLANE + p];
    }
    __syncthreads();

    uint* dst = tf + ((size_t)(b * TT + t) * HWSZ + p0) * (CIN / 2);
    #pragma unroll
    for (int it = 0; it < 4; ++it) {
        int i  = it * 256 + threadIdx.x;   // 0..1023
        int p  = i >> 4, c2 = i & 15;
        dst[p * 16 + c2] = pk_bf16(tile[2 * c2][p], tile[2 * c2 + 1][p]);
    }
}

// ---------------------------------------------------------------------------
// weight f32 [T][o=32][c=32][k=9] -> wfrag bf16 [t][k][n][lane][j]
//   B-frag element: B[k_dim = (lane>>4)*8 + j][n = ntile*16 + (lane&15)]
// ---------------------------------------------------------------------------
__global__ __launch_bounds__(256) void wprep_kernel(
    const float* __restrict__ wt, ushort* __restrict__ wfrag)
{
    int idx = blockIdx.x * 256 + threadIdx.x;
    if (idx >= TT * KK * 2 * 64 * 8) return;
    int t  = idx / (KK * 1024);
    int f  = idx % (KK * 1024);
    int k  = f >> 10;
    int r2 = f & 1023;
    int n    = r2 >> 9;
    int lane = (r2 >> 3) & 63;
    int j    = r2 & 7;
    int o = n * 16 + (lane & 15);
    int c = (lane >> 4) * 8 + j;
    float v = wt[(((size_t)t * COUT + o) * CIN + c) * KK + k];
    __hip_bfloat16 hb = __float2bfloat16(v);
    union { __hip_bfloat16 b; ushort u; } cv; cv.b = hb;
    wfrag[idx] = cv.u;
}

// ---------------------------------------------------------------------------
// Main MFMA kernel. Block 256 thr = 4 waves. Tile 32x8 pixels.
// Wave wv owns rows h0+2wv, h0+2wv+1; 4 M-tiles of 16 pixels each.
// ---------------------------------------------------------------------------
__global__ __launch_bounds__(256, 2) void dcn_mfma_kernel(
    const uint* __restrict__ tf,        // bf16 channels-last [bt][pix][c/2]
    const float* __restrict__ offset,
    const ushort* __restrict__ wfrag,
    float* __restrict__ out)
{
    __shared__ uint4 halo[HROWS * HCOLS * 5];   // 55760 B

    const int tid  = threadIdx.x;
    const int lane = tid & 63;
    const int wv   = tid >> 6;
    const int lane15 = lane & 15;
    const int quad   = lane >> 4;

    const int w0 = blockIdx.x * TILE_W;
    const int h0 = blockIdx.y * TILE_H;
    const int bt = blockIdx.z;
    const int t  = bt & (TT - 1);
    const int b  = bt >> 3;

    const int hlo = h0 - HALO, wlo = w0 - HALO;
    const int hhi = hlo + (HROWS - 1), whi = wlo + (HCOLS - 1);

    const uint4* tfs4 = (const uint4*)tf + (size_t)bt * HWSZ * 4;  // 4 uint4/pixel

    // ---- stage halo (edge-replicated) into LDS ----
    #pragma unroll
    for (int it = 0; it < 11; ++it) {
        int idx = it * 256 + tid;
        if (idx < HROWS * HCOLS * 4) {
            int r    = idx / (HCOLS * 4);
            int rem  = idx - r * (HCOLS * 4);
            int pv   = rem >> 2;
            int part = rem & 3;
            int gy = min(max(hlo + r, 0), HH - 1);
            int gx = min(max(wlo + pv, 0), WW - 1);
            halo[(r * HCOLS + pv) * 5 + part] = tfs4[(gy * WW + gx) * 4 + part];
        }
    }

    // ---- load per-pixel offsets into registers (lane owns one pixel) ----
    float offv[2 * KK];
    {
        const int orow = h0 + 2 * wv + (lane >> 5);
        const int ocol = w0 + (lane & 31);
        const float* offp = offset + (size_t)b * 2 * KK * PLANE
                          + (size_t)t * HWSZ + orow * WW + ocol;
        #pragma unroll
        for (int j = 0; j < 2 * KK; ++j) offv[j] = offp[(size_t)j * PLANE];
    }

    // ---- load B-fragments (weights) into registers ----
    short8 bfr[KK][2];
    {
        const uint4* wfp = (const uint4*)(wfrag + (size_t)t * KK * 2 * 64 * 8);
        #pragma unroll
        for (int k = 0; k < KK; ++k)
            #pragma unroll
            for (int n = 0; n < 2; ++n) {
                U4S8 cv; cv.u = wfp[(k * 2 + n) * 64 + lane];
                bfr[k][n] = cv.s;
            }
    }

    __syncthreads();

    f32x4 acc[4][2];
    #pragma unroll
    for (int i = 0; i < 4; ++i)
        #pragma unroll
        for (int n = 0; n < 2; ++n) {
            acc[i][n][0] = 0.f; acc[i][n][1] = 0.f;
            acc[i][n][2] = 0.f; acc[i][n][3] = 0.f;
        }

    int own[4];
    #pragma unroll
    for (int i = 0; i < 4; ++i) own[i] = ((i >> 1) << 5) | ((i & 1) << 4) | lane15;

    #pragma unroll
    for (int k = 0; k < KK; ++k) {
        const int ky = k / 3 - 1;
        const int kx = k % 3 - 1;
        #pragma unroll
        for (int i = 0; i < 4; ++i) {
            const float dy = __shfl(offv[2 * k],     own[i], 64);
            const float dx = __shfl(offv[2 * k + 1], own[i], 64);
            const int hp = h0 + 2 * wv + (i >> 1);
            const int wp = w0 + ((i & 1) << 4) + lane15;

            const float ys = (float)(hp + ky) + dy;
            const float xs = (float)(wp + kx) + dx;
            const float y0f = floorf(ys), x0f = floorf(xs);
            const float wy1 = ys - y0f,  wx1 = xs - x0f;
            const float wy0 = 1.f - wy1, wx0 = 1.f - wx1;

            const int y0 = (int)y0f, x0i = (int)x0f;
            const int y1 = y0 + 1,   x1 = x0i + 1;

            const float vy0 = (y0 >= 0 && y0 < HH) ? 1.f : 0.f;
            const float vy1 = (y1 >= 0 && y1 < HH) ? 1.f : 0.f;
            const float vx0 = (x0i >= 0 && x0i < WW) ? 1.f : 0.f;
            const float vx1 = (x1 >= 0 && x1 < WW) ? 1.f : 0.f;

            const int cy0 = min(max(y0, 0), HH - 1);
            const int cy1 = min(max(y1, 0), HH - 1);
            const int cx0 = min(max(x0i, 0), WW - 1);
            const int cx1 = min(max(x1, 0), WW - 1);

            const float w00 = wy0 * wx0 * vy0 * vx0;
            const float w01 = wy0 * wx1 * vy0 * vx1;
            const float w10 = wy1 * wx0 * vy1 * vx0;
            const float w11 = wy1 * wx1 * vy1 * vx1;

            const bool inH = (cy0 >= hlo) & (cy1 <= hhi) & (cx0 >= wlo) & (cx1 <= whi);

            uint4 q00, q01, q10, q11;
            if (inH) {
                const int r0 = cy0 - hlo, r1 = cy1 - hlo;
                const int c0 = cx0 - wlo, c1 = cx1 - wlo;
                q00 = halo[(r0 * HCOLS + c0) * 5 + quad];
                q01 = halo[(r0 * HCOLS + c1) * 5 + quad];
                q10 = halo[(r1 * HCOLS + c0) * 5 + quad];
                q11 = halo[(r1 * HCOLS + c1) * 5 + quad];
            } else {
                q00 = tfs4[(cy0 * WW + cx0) * 4 + quad];
                q01 = tfs4[(cy0 * WW + cx1) * 4 + quad];
                q10 = tfs4[(cy1 * WW + cx0) * 4 + quad];
                q11 = tfs4[(cy1 * WW + cx1) * 4 + quad];
            }

            U4S8 af;
            af.u.x = blerp_pack(q00.x, q01.x, q10.x, q11.x, w00, w01, w10, w11);
            af.u.y = blerp_pack(q00.y, q01.y, q10.y, q11.y, w00, w01, w10, w11);
            af.u.z = blerp_pack(q00.z, q01.z, q10.z, q11.z, w00, w01, w10, w11);
            af.u.w = blerp_pack(q00.w, q01.w, q10.w, q11.w, w00, w01, w10, w11);

            acc[i][0] = __builtin_amdgcn_mfma_f32_16x16x32_bf16(af.s, bfr[k][0], acc[i][0], 0, 0, 0);
            acc[i][1] = __builtin_amdgcn_mfma_f32_16x16x32_bf16(af.s, bfr[k][1], acc[i][1], 0, 0, 0);
        }
    }

    // ---- epilogue: D[m][n]: n(col)=lane&15 -> o; m(row)=quad*4+r -> pixel ----
    float* ob = out + (size_t)b * COUT * PLANE + (size_t)t * HWSZ;
    #pragma unroll
    for (int i = 0; i < 4; ++i) {
        const int hp    = h0 + 2 * wv + (i >> 1);
        const int wbase = w0 + ((i & 1) << 4) + quad * 4;
        #pragma unroll
        for (int n = 0; n < 2; ++n) {
            const int o = n * 16 + lane15;
            float* op = ob + (size_t)o * PLANE + hp * WW + wbase;
            #pragma unroll
            for (int r = 0; r < 4; ++r) op[r] = acc[i][n][r];
        }
    }
}

// ---------------------------------------------------------------------------
// Round-1 fallback (known-correct) if ws_size is too small.
// ---------------------------------------------------------------------------
__global__ __launch_bounds__(256) void dcn_fp32_kernel(
    const float* __restrict__ feat,
    const float* __restrict__ offset,
    const float* __restrict__ weight,
    float* __restrict__ out)
{
    __shared__ float sw[KK * CIN * COUT];
    const int tid = threadIdx.x;
    const int t   = blockIdx.y;
    const int b   = blockIdx.z;
    {
        const float* wg = weight + (size_t)t * (COUT * CIN * KK);
        #pragma unroll
        for (int j = 0; j < (KK * CIN * COUT) / 256; ++j) {
            int i  = tid + j * 256;
            int k  = i % KK;
            int oc = i / KK;
            sw[(k * CIN + (oc % CIN)) * COUT + (oc / CIN)] = wg[i];
        }
    }
    __syncthreads();

    const int pix = blockIdx.x * 256 + tid;
    const int h   = pix / WW;
    const int w   = pix % WW;

    float acc[COUT];
    #pragma unroll
    for (int o = 0; o < COUT; ++o) acc[o] = 0.0f;

    const float* offp = offset + ((size_t)(b * 2 * KK) * TT + t) * HWSZ + pix;
    float offv[2 * KK];
    #pragma unroll
    for (int j = 0; j < 2 * KK; ++j) offv[j] = offp[(size_t)j * PLANE];

    const float* fbase = feat + ((size_t)(b * CIN) * TT + t) * HWSZ;

    for (int k = 0; k < KK; ++k) {
        const float ys = (float)(h + k / 3 - 1) + offv[2 * k];
        const float xs = (float)(w + k % 3 - 1) + offv[2 * k + 1];
        const float y0f = floorf(ys), x0f = floorf(xs);
        const float wy1 = ys - y0f, wx1 = xs - x0f;
        const float wy0 = 1.0f - wy1, wx0 = 1.0f - wx1;
        const int y0 = (int)y0f, x0 = (int)x0f, y1 = y0 + 1, x1 = x0 + 1;
        const bool vy0 = (y0 >= 0) && (y0 < HH), vy1 = (y1 >= 0) && (y1 < HH);
        const bool vx0 = (x0 >= 0) && (x0 < WW), vx1 = (x1 >= 0) && (x1 < WW);
        const int cy0 = min(max(y0, 0), HH - 1), cy1 = min(max(y1, 0), HH - 1);
        const int cx0 = min(max(x0, 0), WW - 1), cx1 = min(max(x1, 0), WW - 1);
        const float w00 = wy0 * wx0 * ((vy0 && vx0) ? 1.0f : 0.0f);
        const float w01 = wy0 * wx1 * ((vy0 && vx1) ? 1.0f : 0.0f);
        const float w10 = wy1 * wx0 * ((vy1 && vx0) ? 1.0f : 0.0f);
        const float w11 = wy1 * wx1 * ((vy1 && vx1) ? 1.0f : 0.0f);
        const int i00 = cy0 * WW + cx0, i01 = cy0 * WW + cx1;
        const int i10 = cy1 * WW + cx0, i11 = cy1 * WW + cx1;

        const float*  sp   = fbase;
        const float4* wrow = (const float4*)&sw[k * CIN * COUT];
        for (int c = 0; c < CIN; ++c) {
            const float v = w00 * sp[i00] + w01 * sp[i01]
                          + w10 * sp[i10] + w11 * sp[i11];
            const float4* wp = wrow + c * (COUT / 4);
            #pragma unroll
            for (int o4 = 0; o4 < COUT / 4; ++o4) {
                const float4 wv = wp[o4];
                acc[4 * o4 + 0] += v * wv.x;
                acc[4 * o4 + 1] += v * wv.y;
                acc[4 * o4 + 2] += v * wv.z;
                acc[4 * o4 + 3] += v * wv.w;
            }
            sp += PLANE;
        }
    }

    float* op = out + ((size_t)(b * COUT) * TT + t) * HWSZ + pix;
    #pragma unroll
    for (int o = 0; o < COUT; ++o) op[(size_t)o * PLANE] = acc[o];
}

extern "C" void kernel_launch(void* const* d_in, const int* in_sizes, int n_in,
                              void* d_out, int out_size, void* d_ws, size_t ws_size,
                              hipStream_t stream) {
    const float* feat   = (const float*)d_in[0];
    const float* offset = (const float*)d_in[1];
    const float* weight = (const float*)d_in[2];
    float* out = (float*)d_out;

    const size_t tf_bytes = (size_t)2 * TT * HWSZ * CIN * sizeof(ushort);  // 37.75 MB
    const size_t wf_bytes = (size_t)TT * KK * 2 * 64 * 8 * sizeof(ushort); // 147 KB

    if (ws_size >= tf_bytes + wf_bytes) {
        uint*   tf    = (uint*)d_ws;
        ushort* wfrag = (ushort*)((char*)d_ws + tf_bytes);

        transpose_bf16_kernel<<<dim3(HWSZ / 64, TT, 2), dim3(256), 0, stream>>>(feat, tf);
        wprep_kernel<<<dim3((TT * KK * 2 * 64 * 8 + 255) / 256), dim3(256), 0, stream>>>(weight, wfrag);
        dcn_mfma_kernel<<<dim3(WW / TILE_W, HH / TILE_H, 2 * TT), dim3(256), 0, stream>>>(
            tf, offset, wfrag, out);
    } else {
        dcn_fp32_kernel<<<dim3(HWSZ / 256, TT, 2), dim3(256), 0, stream>>>(feat, offset, weight, out);
    }
}